// Round 1
// baseline (11023.942 us; speedup 1.0000x reference)
//
#include <hip/hip_runtime.h>

typedef __attribute__((ext_vector_type(8))) short bf16x8;
typedef __attribute__((ext_vector_type(4))) float f32x4;

__device__ __forceinline__ short f2bf(float f) {
  union { float f; unsigned u; } v; v.f = f;
  unsigned r = (v.u + 0x7fffu + ((v.u >> 16) & 1u)) >> 16;
  return (short)r;
}
__device__ __forceinline__ float bf2f(short s) {
  union { unsigned u; float f; } v; v.u = ((unsigned)(unsigned short)s) << 16;
  return v.f;
}
__device__ __forceinline__ float sigmf(float x) { return 1.f / (1.f + __expf(-x)); }

// stage 16 fp32 -> bf16 into LDS row, zero-padding past K
__device__ __forceinline__ void stage_row_f32(const float* __restrict__ src, short* dst,
                                              int kb, int k0, int K) {
  if (kb + k0 + 15 < K) {
    const f32x4* p4 = (const f32x4*)src;
#pragma unroll
    for (int g = 0; g < 4; g++) {
      f32x4 v = p4[g];
      dst[g * 4 + 0] = f2bf(v.x); dst[g * 4 + 1] = f2bf(v.y);
      dst[g * 4 + 2] = f2bf(v.z); dst[g * 4 + 3] = f2bf(v.w);
    }
  } else {
#pragma unroll
    for (int j = 0; j < 16; j++) {
      float v = (kb + k0 + j < K) ? src[j] : 0.f;
      dst[j] = f2bf(v);
    }
  }
}

// C[m][n] = act( sum_k A[m][k] * W[n][k] + bias[n] ), C stored bf16 at ldc/coloff.
// MODE==1: A row r maps to physical row (r&31)*256 + (r>>5)  ([B=32,T=256,*] -> (t,b) order)
// M = grid.x*128 (exact), N = grid.y*128 (exact). K arbitrary (zero-padded per 32-chunk).
template <typename AT, int MODE>
__global__ __launch_bounds__(256) void gemm_bf16(
    const AT* __restrict__ A, int lda,
    const float* __restrict__ W, int ldw,
    const float* __restrict__ bias,
    short* __restrict__ C, int ldc, int coloff, int K, int act) {
  __shared__ short As[128][40];
  __shared__ short Bs[128][40];
  const int tid = threadIdx.x;
  const int m0 = blockIdx.x << 7, n0 = blockIdx.y << 7;
  const int w = tid >> 6, lane = tid & 63, m16 = lane & 15, q = lane >> 4;
  const f32x4 vzero = {0.f, 0.f, 0.f, 0.f};
  f32x4 acc[2][8];
#pragma unroll
  for (int mt = 0; mt < 2; mt++)
#pragma unroll
    for (int nt = 0; nt < 8; nt++) acc[mt][nt] = vzero;

  const int nk = (K + 31) >> 5;
  const int r = tid >> 1, k0 = (tid & 1) << 4;
  for (int kc = 0; kc < nk; kc++) {
    const int kb = kc << 5;
    {  // stage A tile [128 x 32]
      const int gr = m0 + r;
      const size_t arow = (MODE == 1) ? ((size_t)(gr & 31) * 256 + (size_t)(gr >> 5))
                                      : (size_t)gr;
      const AT* ap = A + arow * (size_t)lda + kb + k0;
      if constexpr (sizeof(AT) == 2) {  // bf16 input, K multiple of 32
        *(bf16x8*)&As[r][k0] = *(const bf16x8*)ap;
        *(bf16x8*)&As[r][k0 + 8] = *(const bf16x8*)(ap + 8);
      } else {
        stage_row_f32((const float*)ap, &As[r][k0], kb, k0, K);
      }
    }
    {  // stage B tile [128 x 32] from fp32 W
      const float* bp = W + (size_t)(n0 + r) * ldw + kb + k0;
      stage_row_f32(bp, &Bs[r][k0], kb, k0, K);
    }
    __syncthreads();
    bf16x8 af[2], bfv[8];
#pragma unroll
    for (int mt = 0; mt < 2; mt++)
      af[mt] = *(const bf16x8*)&As[(w << 5) + (mt << 4) + m16][q << 3];
#pragma unroll
    for (int nt = 0; nt < 8; nt++)
      bfv[nt] = *(const bf16x8*)&Bs[(nt << 4) + m16][q << 3];
#pragma unroll
    for (int mt = 0; mt < 2; mt++)
#pragma unroll
      for (int nt = 0; nt < 8; nt++)
        acc[mt][nt] = __builtin_amdgcn_mfma_f32_16x16x32_bf16(af[mt], bfv[nt], acc[mt][nt], 0, 0, 0);
    __syncthreads();
  }
  // epilogue: C/D layout col=lane&15, row=q*4+i
#pragma unroll
  for (int mt = 0; mt < 2; mt++)
#pragma unroll
    for (int nt = 0; nt < 8; nt++)
#pragma unroll
      for (int i = 0; i < 4; i++) {
        const int grow = m0 + (w << 5) + (mt << 4) + (q << 2) + i;
        const int gcol = n0 + (nt << 4) + m16;
        float v = acc[mt][nt][i];
        if (bias) v += bias[gcol];
        if (act) v = fmaxf(v, 0.f);
        C[(size_t)grow * ldc + coloff + gcol] = f2bf(v);
      }
}

// Persistent GRU recurrence for one layer, both chains.
// grid = 128 blocks: blocks [0,64) = fwd chain, [64,128) = bwd chain.
// Block g owns d-range [g*16, g*16+16): Whh rows {d, 1024+d, 2048+d} kept in VGPRs
// as MFMA A-frags. Per step: hg = Whh_slice @ y[t-1]^T via mfma (4-way K-split over
// waves), LDS-reduce, fp32 gate elementwise (h carried in fp32 regs), write y[t] bf16,
// device-scope sense barrier per chain (64 blocks, all co-resident: 1 block/CU).
__global__ __launch_bounds__(256, 1) void gru_recur(
    const float* __restrict__ Whh_f, const float* __restrict__ Whh_b,
    const float* __restrict__ bih_fp, const float* __restrict__ bhh_fp,
    const float* __restrict__ bih_bp, const float* __restrict__ bhh_bp,
    const short* __restrict__ xg_f, const short* __restrict__ xg_b,
    short* y_f, short* y_b,
    int* bars) {
  const int chain = blockIdx.x >> 6;
  const int g = blockIdx.x & 63;
  const int d0 = g << 4;
  const float* Whh = chain ? Whh_b : Whh_f;
  const float* bih = chain ? bih_bp : bih_fp;
  const float* bhh = chain ? bhh_bp : bhh_fp;
  const short* xg = chain ? xg_b : xg_f;
  short* y = chain ? y_b : y_f;
  int* bar = bars + chain * 2;

  const int tid = threadIdx.x;
  const int w = tid >> 6, lane = tid & 63, m16 = lane & 15, q = lane >> 4;
  const int kw = w << 8;  // wave's K-slice base (256 each)

  // ---- preload Whh slice as A-frags (fp32 -> bf16), 24 frags = 96 VGPRs ----
  bf16x8 a[3][8];
#pragma unroll
  for (int mt = 0; mt < 3; mt++) {
    const int row = mt * 1024 + d0 + m16;
#pragma unroll
    for (int ks = 0; ks < 8; ks++) {
      const int kk = kw + ks * 32 + (q << 3);
      const f32x4* wp = (const f32x4*)(Whh + (size_t)row * 1024 + kk);
      f32x4 lo = wp[0], hi = wp[1];
      bf16x8 t;
      t[0] = f2bf(lo.x); t[1] = f2bf(lo.y); t[2] = f2bf(lo.z); t[3] = f2bf(lo.w);
      t[4] = f2bf(hi.x); t[5] = f2bf(hi.y); t[6] = f2bf(hi.z); t[7] = f2bf(hi.w);
      a[mt][ks] = t;
    }
  }

  // elementwise ownership: thread -> (d = tid&15, b in {tid>>4, (tid>>4)+16})
  const int dd = tid & 15, bb = tid >> 4;
  const float Cr = bih[d0 + dd] + bhh[d0 + dd];
  const float Cz = bih[1024 + d0 + dd] + bhh[1024 + d0 + dd];
  const float bni = bih[2048 + d0 + dd], bnh = bhh[2048 + d0 + dd];
  float h1 = 0.f, h2 = 0.f;  // fp32 carry, lives in registers across all steps

  __shared__ float hgp[4][48][33];  // per-wave partials, padded (conflict-free)
  const f32x4 vzero = {0.f, 0.f, 0.f, 0.f};

  for (int t = 0; t < 256; t++) {
    f32x4 acc[3][2];
#pragma unroll
    for (int mt = 0; mt < 3; mt++) { acc[mt][0] = vzero; acc[mt][1] = vzero; }

    if (t > 0) {
      const short* yp = y + (size_t)(t - 1) * 32 * 1024;
      bf16x8 bfr[2][8];
#pragma unroll
      for (int nt = 0; nt < 2; nt++) {
        const int n = (nt << 4) + m16;
#pragma unroll
        for (int ks = 0; ks < 8; ks++)
          bfr[nt][ks] = *(const bf16x8*)(yp + (size_t)n * 1024 + kw + ks * 32 + (q << 3));
      }
#pragma unroll
      for (int ks = 0; ks < 8; ks++)
#pragma unroll
        for (int mt = 0; mt < 3; mt++)
#pragma unroll
          for (int nt = 0; nt < 2; nt++)
            acc[mt][nt] = __builtin_amdgcn_mfma_f32_16x16x32_bf16(a[mt][ks], bfr[nt][ks], acc[mt][nt], 0, 0, 0);
    }
#pragma unroll
    for (int mt = 0; mt < 3; mt++)
#pragma unroll
      for (int nt = 0; nt < 2; nt++)
#pragma unroll
        for (int i = 0; i < 4; i++)
          hgp[w][mt * 16 + (q << 2) + i][(nt << 4) + m16] = acc[mt][nt][i];
    __syncthreads();

    {  // gates for both (d,b) pairs
      float hr0 = 0.f, hz0 = 0.f, hn0 = 0.f, hr1 = 0.f, hz1 = 0.f, hn1 = 0.f;
#pragma unroll
      for (int ww = 0; ww < 4; ww++) {
        hr0 += hgp[ww][dd][bb];      hr1 += hgp[ww][dd][bb + 16];
        hz0 += hgp[ww][16 + dd][bb]; hz1 += hgp[ww][16 + dd][bb + 16];
        hn0 += hgp[ww][32 + dd][bb]; hn1 += hgp[ww][32 + dd][bb + 16];
      }
      const short* x0p = xg + ((size_t)t * 32 + bb) * 3072 + d0;
      const short* x1p = xg + ((size_t)t * 32 + bb + 16) * 3072 + d0;
      {
        float rr = sigmf(bf2f(x0p[dd]) + Cr + hr0);
        float zz = sigmf(bf2f(x0p[1024 + dd]) + Cz + hz0);
        float nn = tanhf(bf2f(x0p[2048 + dd]) + bni + rr * (hn0 + bnh));
        h1 = (1.f - zz) * nn + zz * h1;
        y[((size_t)t * 32 + bb) * 1024 + d0 + dd] = f2bf(h1);
      }
      {
        float rr = sigmf(bf2f(x1p[dd]) + Cr + hr1);
        float zz = sigmf(bf2f(x1p[1024 + dd]) + Cz + hz1);
        float nn = tanhf(bf2f(x1p[2048 + dd]) + bni + rr * (hn1 + bnh));
        h2 = (1.f - zz) * nn + zz * h2;
        y[((size_t)t * 32 + bb + 16) * 1024 + d0 + dd] = f2bf(h2);
      }
    }

    // ---- device-scope barrier (per chain, 64 blocks) ----
    __threadfence();
    __syncthreads();
    if (tid == 0) {
      const int target = t + 1;
      const int arrived = __hip_atomic_fetch_add(&bar[0], 1, __ATOMIC_ACQ_REL, __HIP_MEMORY_SCOPE_AGENT);
      if (arrived == 63) {
        __hip_atomic_store(&bar[0], 0, __ATOMIC_RELAXED, __HIP_MEMORY_SCOPE_AGENT);
        __hip_atomic_store(&bar[1], target, __ATOMIC_RELEASE, __HIP_MEMORY_SCOPE_AGENT);
      }
      // everyone (incl. last arriver) does an acquire load -> L1 invalidate
      while (__hip_atomic_load(&bar[1], __ATOMIC_ACQUIRE, __HIP_MEMORY_SCOPE_AGENT) < target) {
        __builtin_amdgcn_s_sleep(2);
      }
    }
    __syncthreads();
  }
}

__global__ __launch_bounds__(256) void final_dot(
    const short* __restrict__ yF, const short* __restrict__ yB,
    const float* __restrict__ Wo, const float* __restrict__ bo,
    float* __restrict__ partials) {
  const int w = threadIdx.x >> 6, lane = threadIdx.x & 63;
  __shared__ float red[4];
  float acc = 0.f;
  const int r0 = (blockIdx.x << 7) + (w << 5);
  for (int rr = 0; rr < 32; rr++) {
    const size_t rrow = (size_t)(r0 + rr);
    const short* f = yF + rrow * 1024;
    const short* gp = yB + rrow * 1024;
    float s = 0.f;
    for (int c = lane; c < 1024; c += 64) s += (bf2f(f[c]) + bf2f(gp[c])) * Wo[c];
#pragma unroll
    for (int off = 32; off > 0; off >>= 1) s += __shfl_down(s, off);
    if (lane == 0) acc += sigmf(s + bo[0]);
  }
  if (lane == 0) red[w] = acc;
  __syncthreads();
  if (threadIdx.x == 0) partials[blockIdx.x] = red[0] + red[1] + red[2] + red[3];
}

__global__ void final_reduce(const float* __restrict__ partials, float* __restrict__ out) {
  float s = partials[threadIdx.x];  // 64 blocks' partials, 64 threads
#pragma unroll
  for (int off = 32; off > 0; off >>= 1) s += __shfl_down(s, off);
  if (threadIdx.x == 0) out[0] = s * (1.f / 8192.f);
}

extern "C" void kernel_launch(void* const* d_in, const int* in_sizes, int n_in,
                              void* d_out, int out_size, void* d_ws, size_t ws_size,
                              hipStream_t stream) {
  const float* in_x  = (const float*)d_in[0];   // [32,256,72]
  const float* in_c  = (const float*)d_in[1];   // [32,256,80]
  const float* Wc    = (const float*)d_in[2];   // [512,80]
  const float* bc    = (const float*)d_in[3];
  const float* Wi    = (const float*)d_in[4];   // [512,72]
  const float* bi    = (const float*)d_in[5];
  const float* Wih_f = (const float*)d_in[6];   // [2,3072,1024]
  const float* Whh_f = (const float*)d_in[7];
  const float* bih_f = (const float*)d_in[8];
  const float* bhh_f = (const float*)d_in[9];
  const float* Wih_b = (const float*)d_in[10];
  const float* Whh_b = (const float*)d_in[11];
  const float* bih_b = (const float*)d_in[12];
  const float* bhh_b = (const float*)d_in[13];
  const float* Wo    = (const float*)d_in[14];  // [1,1024]
  const float* bo    = (const float*)d_in[15];
  float* out = (float*)d_out;

  char* base = (char*)d_ws;
  const size_t S1 = (size_t)8192 * 1024 * 2;  // 16.78 MB (bf16 [T*B,1024])
  const size_t S2 = (size_t)8192 * 3072 * 2;  // 50.33 MB (bf16 [T*B,3072])
  short* x0  = (short*)(base);                // layer-0 input; reused as y1f
  short* y0f = (short*)(base + S1);
  short* y0b = (short*)(base + 2 * S1);
  short* y1b = (short*)(base + 3 * S1);
  short* xgf = (short*)(base + 4 * S1);
  short* xgb = (short*)(base + 4 * S1 + S2);
  float* partials = (float*)(base + 4 * S1 + 2 * S2);
  int* bars = (int*)(base + 4 * S1 + 2 * S2 + 4096);
  short* y1f = x0;
  // total ws use: 4*S1 + 2*S2 + ~8KB  ~= 167.8 MB

  hipMemsetAsync(bars, 0, 64, stream);

  dim3 blk(256);
  // input projections -> x0[t*32+b][0:512 | 512:1024], relu
  gemm_bf16<float, 1><<<dim3(64, 4), blk, 0, stream>>>(in_c, 80, Wc, 80, bc, x0, 1024, 0, 80, 1);
  gemm_bf16<float, 1><<<dim3(64, 4), blk, 0, stream>>>(in_x, 72, Wi, 72, bi, x0, 1024, 512, 72, 1);
  // layer 0: xg = x0 @ Wih^T, then recurrence
  gemm_bf16<short, 0><<<dim3(64, 24), blk, 0, stream>>>(x0, 1024, Wih_f, 1024, nullptr, xgf, 3072, 0, 1024, 0);
  gemm_bf16<short, 0><<<dim3(64, 24), blk, 0, stream>>>(x0, 1024, Wih_b, 1024, nullptr, xgb, 3072, 0, 1024, 0);
  gru_recur<<<dim3(128), blk, 0, stream>>>(Whh_f, Whh_b, bih_f, bhh_f, bih_b, bhh_b,
                                           xgf, xgb, y0f, y0b, bars);
  // layer 1
  const size_t WO = (size_t)3072 * 1024;
  gemm_bf16<short, 0><<<dim3(64, 24), blk, 0, stream>>>(y0f, 1024, Wih_f + WO, 1024, nullptr, xgf, 3072, 0, 1024, 0);
  gemm_bf16<short, 0><<<dim3(64, 24), blk, 0, stream>>>(y0b, 1024, Wih_b + WO, 1024, nullptr, xgb, 3072, 0, 1024, 0);
  gru_recur<<<dim3(128), blk, 0, stream>>>(Whh_f + WO, Whh_b + WO, bih_f + 3072, bhh_f + 3072,
                                           bih_b + 3072, bhh_b + 3072,
                                           xgf, xgb, y1f, y1b, bars + 4);
  // out = mean(sigmoid((y1f+y1b) @ Wo^T + bo))
  final_dot<<<dim3(64), blk, 0, stream>>>(y1f, y1b, Wo, bo, partials);
  final_reduce<<<dim3(1), dim3(64), 0, stream>>>(partials, out);
}

// Round 2
// 5905.961 us; speedup vs baseline: 1.8666x; 1.8666x over previous
//
#include <hip/hip_runtime.h>

typedef __attribute__((ext_vector_type(8))) short bf16x8;
typedef __attribute__((ext_vector_type(4))) float f32x4;

__device__ __forceinline__ short f2bf(float f) {
  union { float f; unsigned u; } v; v.f = f;
  unsigned r = (v.u + 0x7fffu + ((v.u >> 16) & 1u)) >> 16;
  return (short)r;
}
__device__ __forceinline__ float bf2f(short s) {
  union { unsigned u; float f; } v; v.u = ((unsigned)(unsigned short)s) << 16;
  return v.f;
}
__device__ __forceinline__ float sigmf(float x) { return 1.f / (1.f + __expf(-x)); }

// stage 16 fp32 -> bf16 into LDS row, zero-padding past K
__device__ __forceinline__ void stage_row_f32(const float* __restrict__ src, short* dst,
                                              int kb, int k0, int K) {
  if (kb + k0 + 15 < K) {
    const f32x4* p4 = (const f32x4*)src;
#pragma unroll
    for (int g = 0; g < 4; g++) {
      f32x4 v = p4[g];
      dst[g * 4 + 0] = f2bf(v.x); dst[g * 4 + 1] = f2bf(v.y);
      dst[g * 4 + 2] = f2bf(v.z); dst[g * 4 + 3] = f2bf(v.w);
    }
  } else {
#pragma unroll
    for (int j = 0; j < 16; j++) {
      float v = (kb + k0 + j < K) ? src[j] : 0.f;
      dst[j] = f2bf(v);
    }
  }
}

// C[m][n] = act( sum_k A[m][k] * W[n][k] + bias[n] ), C stored bf16 at ldc/coloff.
// MODE==1: A row r maps to physical row (r&31)*256 + (r>>5)  ([B=32,T=256,*] -> (t,b) order)
template <typename AT, int MODE>
__global__ __launch_bounds__(256) void gemm_bf16(
    const AT* __restrict__ A, int lda,
    const float* __restrict__ W, int ldw,
    const float* __restrict__ bias,
    short* __restrict__ C, int ldc, int coloff, int K, int act) {
  __shared__ short As[128][40];
  __shared__ short Bs[128][40];
  const int tid = threadIdx.x;
  const int m0 = blockIdx.x << 7, n0 = blockIdx.y << 7;
  const int w = tid >> 6, lane = tid & 63, m16 = lane & 15, q = lane >> 4;
  const f32x4 vzero = {0.f, 0.f, 0.f, 0.f};
  f32x4 acc[2][8];
#pragma unroll
  for (int mt = 0; mt < 2; mt++)
#pragma unroll
    for (int nt = 0; nt < 8; nt++) acc[mt][nt] = vzero;

  const int nk = (K + 31) >> 5;
  const int r = tid >> 1, k0 = (tid & 1) << 4;
  for (int kc = 0; kc < nk; kc++) {
    const int kb = kc << 5;
    {  // stage A tile [128 x 32]
      const int gr = m0 + r;
      const size_t arow = (MODE == 1) ? ((size_t)(gr & 31) * 256 + (size_t)(gr >> 5))
                                      : (size_t)gr;
      const AT* ap = A + arow * (size_t)lda + kb + k0;
      if constexpr (sizeof(AT) == 2) {
        *(bf16x8*)&As[r][k0] = *(const bf16x8*)ap;
        *(bf16x8*)&As[r][k0 + 8] = *(const bf16x8*)(ap + 8);
      } else {
        stage_row_f32((const float*)ap, &As[r][k0], kb, k0, K);
      }
    }
    {  // stage B tile [128 x 32] from fp32 W
      const float* bp = W + (size_t)(n0 + r) * ldw + kb + k0;
      stage_row_f32(bp, &Bs[r][k0], kb, k0, K);
    }
    __syncthreads();
    bf16x8 af[2], bfv[8];
#pragma unroll
    for (int mt = 0; mt < 2; mt++)
      af[mt] = *(const bf16x8*)&As[(w << 5) + (mt << 4) + m16][q << 3];
#pragma unroll
    for (int nt = 0; nt < 8; nt++)
      bfv[nt] = *(const bf16x8*)&Bs[(nt << 4) + m16][q << 3];
#pragma unroll
    for (int mt = 0; mt < 2; mt++)
#pragma unroll
      for (int nt = 0; nt < 8; nt++)
        acc[mt][nt] = __builtin_amdgcn_mfma_f32_16x16x32_bf16(af[mt], bfv[nt], acc[mt][nt], 0, 0, 0);
    __syncthreads();
  }
#pragma unroll
  for (int mt = 0; mt < 2; mt++)
#pragma unroll
    for (int nt = 0; nt < 8; nt++)
#pragma unroll
      for (int i = 0; i < 4; i++) {
        const int grow = m0 + (w << 5) + (mt << 4) + (q << 2) + i;
        const int gcol = n0 + (nt << 4) + m16;
        float v = acc[mt][nt][i];
        if (bias) v += bias[gcol];
        if (act) v = fmaxf(v, 0.f);
        C[(size_t)grow * ldc + coloff + gcol] = f2bf(v);
      }
}

// Persistent GRU recurrence, one layer, both chains.
// grid = 64 blocks: [0,32) fwd, [32,64) bwd. Block g owns d-range [g*32, g*32+32).
// Whh rows {d, 1024+d, 2048+d} live in VGPRs as MFMA A-frags (~192 VGPRs).
// ALL h (y) traffic uses RELAXED agent-scope atomics: global_load/store sc0 sc1 ->
// bypass L1/L2, operate at coherence point. NO acquire/release fences -> L2 stays
// warm with xg across all 256 steps (round-0 bug: acq/rel fences nuked L2 every step,
// 340 MB refetch/dispatch, 20.6 us/step).
__global__ __launch_bounds__(256, 1) void gru_recur(
    const float* __restrict__ Whh_f, const float* __restrict__ Whh_b,
    const float* __restrict__ bih_fp, const float* __restrict__ bhh_fp,
    const float* __restrict__ bih_bp, const float* __restrict__ bhh_bp,
    const short* __restrict__ xg_f, const short* __restrict__ xg_b,
    short* y_f, short* y_b,
    int* bars) {
  const int chain = blockIdx.x >> 5;
  const int g = blockIdx.x & 31;
  const int d0 = g << 5;
  const float* Whh = chain ? Whh_b : Whh_f;
  const float* bih = chain ? bih_bp : bih_fp;
  const float* bhh = chain ? bhh_bp : bhh_fp;
  const short* xg = chain ? xg_b : xg_f;
  short* y = chain ? y_b : y_f;
  int* bar = bars + chain * 16;  // separate cache lines per chain

  const int tid = threadIdx.x;
  const int w = tid >> 6, lane = tid & 63, m16 = lane & 15, q = lane >> 4;
  const int kw = w << 8;  // wave's K-slice base (256 each)

  // ---- preload Whh slice as A-frags (fp32 -> bf16): 6 tiles x 8 ksteps ----
  bf16x8 a[6][8];
#pragma unroll
  for (int mt = 0; mt < 6; mt++) {
    const int row = (mt >> 1) * 1024 + d0 + ((mt & 1) << 4) + m16;
#pragma unroll
    for (int ks = 0; ks < 8; ks++) {
      const int kk = kw + ks * 32 + (q << 3);
      const f32x4* wp = (const f32x4*)(Whh + (size_t)row * 1024 + kk);
      f32x4 lo = wp[0], hi = wp[1];
      bf16x8 t;
      t[0] = f2bf(lo.x); t[1] = f2bf(lo.y); t[2] = f2bf(lo.z); t[3] = f2bf(lo.w);
      t[4] = f2bf(hi.x); t[5] = f2bf(hi.y); t[6] = f2bf(hi.z); t[7] = f2bf(hi.w);
      a[mt][ks] = t;
    }
  }

  // elementwise ownership: dd = tid&31 (d_local), batches {bq, bq+8, bq+16, bq+24}
  const int dd = tid & 31, bq = tid >> 5;
  const float Cr = bih[d0 + dd] + bhh[d0 + dd];
  const float Cz = bih[1024 + d0 + dd] + bhh[1024 + d0 + dd];
  const float bni = bih[2048 + d0 + dd], bnh = bhh[2048 + d0 + dd];
  float h[4] = {0.f, 0.f, 0.f, 0.f};

  __shared__ float hgp[4][96][33];  // per-wave partials: row = gate*32+d_local, col = b
  __shared__ short hout[32][36];    // staging for vectorized y store
  const f32x4 vzero = {0.f, 0.f, 0.f, 0.f};

  for (int t = 0; t < 256; t++) {
    f32x4 acc[6][2];
#pragma unroll
    for (int mt = 0; mt < 6; mt++) { acc[mt][0] = vzero; acc[mt][1] = vzero; }

    if (t > 0) {
      const short* yp = y + (size_t)(t - 1) * 32 * 1024;
      bf16x8 bfr[2][8];
#pragma unroll
      for (int nt = 0; nt < 2; nt++) {
        const int n = (nt << 4) + m16;
#pragma unroll
        for (int ks = 0; ks < 8; ks++) {
          const size_t off = (size_t)n * 1024 + kw + ks * 32 + (q << 3);
          union { unsigned long long u[2]; bf16x8 v; } pk;
          pk.u[0] = __hip_atomic_load((const unsigned long long*)(yp + off),
                                      __ATOMIC_RELAXED, __HIP_MEMORY_SCOPE_AGENT);
          pk.u[1] = __hip_atomic_load((const unsigned long long*)(yp + off + 4),
                                      __ATOMIC_RELAXED, __HIP_MEMORY_SCOPE_AGENT);
          bfr[nt][ks] = pk.v;
        }
      }
#pragma unroll
      for (int ks = 0; ks < 8; ks++)
#pragma unroll
        for (int mt = 0; mt < 6; mt++)
#pragma unroll
          for (int nt = 0; nt < 2; nt++)
            acc[mt][nt] = __builtin_amdgcn_mfma_f32_16x16x32_bf16(a[mt][ks], bfr[nt][ks], acc[mt][nt], 0, 0, 0);
    }
#pragma unroll
    for (int mt = 0; mt < 6; mt++)
#pragma unroll
      for (int nt = 0; nt < 2; nt++)
#pragma unroll
        for (int i = 0; i < 4; i++)
          hgp[w][mt * 16 + (q << 2) + i][(nt << 4) + m16] = acc[mt][nt][i];
    __syncthreads();

    // gates: 4 (d,b) pairs per thread, h carried in fp32 registers
#pragma unroll
    for (int k = 0; k < 4; k++) {
      const int b = bq + (k << 3);
      float hr = 0.f, hz = 0.f, hn = 0.f;
#pragma unroll
      for (int ww = 0; ww < 4; ww++) {
        hr += hgp[ww][dd][b];
        hz += hgp[ww][32 + dd][b];
        hn += hgp[ww][64 + dd][b];
      }
      const short* xp = xg + ((size_t)t * 32 + b) * 3072 + d0;
      float rr = sigmf(bf2f(xp[dd]) + Cr + hr);
      float zz = sigmf(bf2f(xp[1024 + dd]) + Cz + hz);
      float nn = tanhf(bf2f(xp[2048 + dd]) + bni + rr * (hn + bnh));
      h[k] = (1.f - zz) * nn + zz * h[k];
      hout[b][dd] = f2bf(h[k]);
    }
    __syncthreads();

    // vectorized write-through y store: 8B per thread, bypasses L1/L2
    {
      const int b = tid >> 3, c = (tid & 7) << 2;
      const unsigned long long v = *(const unsigned long long*)&hout[b][c];
      __hip_atomic_store((unsigned long long*)(y + ((size_t)t * 32 + b) * 1024 + d0 + c),
                         v, __ATOMIC_RELAXED, __HIP_MEMORY_SCOPE_AGENT);
    }
    __builtin_amdgcn_s_waitcnt(0);  // my stores have reached the coherence point
    __syncthreads();                // all threads' stores done

    // monotonic-counter barrier, relaxed atomics only (no cache maintenance)
    if (tid == 0) {
      const int target = t + 1;
      const int arrived = __hip_atomic_fetch_add(&bar[0], 1, __ATOMIC_RELAXED,
                                                 __HIP_MEMORY_SCOPE_AGENT);
      if (arrived == target * 32 - 1)
        __hip_atomic_store(&bar[1], target, __ATOMIC_RELAXED, __HIP_MEMORY_SCOPE_AGENT);
      while (__hip_atomic_load(&bar[1], __ATOMIC_RELAXED, __HIP_MEMORY_SCOPE_AGENT) < target)
        __builtin_amdgcn_s_sleep(1);
    }
    __syncthreads();
  }
}

__global__ __launch_bounds__(256) void final_dot(
    const short* __restrict__ yF, const short* __restrict__ yB,
    const float* __restrict__ Wo, const float* __restrict__ bo,
    float* __restrict__ partials) {
  const int w = threadIdx.x >> 6, lane = threadIdx.x & 63;
  __shared__ float red[4];
  float acc = 0.f;
  const int r0 = (blockIdx.x << 7) + (w << 5);
  for (int rr = 0; rr < 32; rr++) {
    const size_t rrow = (size_t)(r0 + rr);
    const short* f = yF + rrow * 1024;
    const short* gp = yB + rrow * 1024;
    float s = 0.f;
    for (int c = lane; c < 1024; c += 64) s += (bf2f(f[c]) + bf2f(gp[c])) * Wo[c];
#pragma unroll
    for (int off = 32; off > 0; off >>= 1) s += __shfl_down(s, off);
    if (lane == 0) acc += sigmf(s + bo[0]);
  }
  if (lane == 0) red[w] = acc;
  __syncthreads();
  if (threadIdx.x == 0) partials[blockIdx.x] = red[0] + red[1] + red[2] + red[3];
}

__global__ void final_reduce(const float* __restrict__ partials, float* __restrict__ out) {
  float s = partials[threadIdx.x];
#pragma unroll
  for (int off = 32; off > 0; off >>= 1) s += __shfl_down(s, off);
  if (threadIdx.x == 0) out[0] = s * (1.f / 8192.f);
}

extern "C" void kernel_launch(void* const* d_in, const int* in_sizes, int n_in,
                              void* d_out, int out_size, void* d_ws, size_t ws_size,
                              hipStream_t stream) {
  const float* in_x  = (const float*)d_in[0];   // [32,256,72]
  const float* in_c  = (const float*)d_in[1];   // [32,256,80]
  const float* Wc    = (const float*)d_in[2];   // [512,80]
  const float* bc    = (const float*)d_in[3];
  const float* Wi    = (const float*)d_in[4];   // [512,72]
  const float* bi    = (const float*)d_in[5];
  const float* Wih_f = (const float*)d_in[6];   // [2,3072,1024]
  const float* Whh_f = (const float*)d_in[7];
  const float* bih_f = (const float*)d_in[8];
  const float* bhh_f = (const float*)d_in[9];
  const float* Wih_b = (const float*)d_in[10];
  const float* Whh_b = (const float*)d_in[11];
  const float* bih_b = (const float*)d_in[12];
  const float* bhh_b = (const float*)d_in[13];
  const float* Wo    = (const float*)d_in[14];  // [1,1024]
  const float* bo    = (const float*)d_in[15];
  float* out = (float*)d_out;

  char* base = (char*)d_ws;
  const size_t S1 = (size_t)8192 * 1024 * 2;  // 16.78 MB (bf16 [T*B,1024])
  const size_t S2 = (size_t)8192 * 3072 * 2;  // 50.33 MB (bf16 [T*B,3072])
  short* x0  = (short*)(base);                // layer-0 input; reused as y1f
  short* y0f = (short*)(base + S1);
  short* y0b = (short*)(base + 2 * S1);
  short* y1b = (short*)(base + 3 * S1);
  short* xgf = (short*)(base + 4 * S1);
  short* xgb = (short*)(base + 4 * S1 + S2);
  float* partials = (float*)(base + 4 * S1 + 2 * S2);
  int* bars = (int*)(base + 4 * S1 + 2 * S2 + 4096);
  short* y1f = x0;

  hipMemsetAsync(bars, 0, 256, stream);

  dim3 blk(256);
  gemm_bf16<float, 1><<<dim3(64, 4), blk, 0, stream>>>(in_c, 80, Wc, 80, bc, x0, 1024, 0, 80, 1);
  gemm_bf16<float, 1><<<dim3(64, 4), blk, 0, stream>>>(in_x, 72, Wi, 72, bi, x0, 1024, 512, 72, 1);
  gemm_bf16<short, 0><<<dim3(64, 24), blk, 0, stream>>>(x0, 1024, Wih_f, 1024, nullptr, xgf, 3072, 0, 1024, 0);
  gemm_bf16<short, 0><<<dim3(64, 24), blk, 0, stream>>>(x0, 1024, Wih_b, 1024, nullptr, xgb, 3072, 0, 1024, 0);
  gru_recur<<<dim3(64), blk, 0, stream>>>(Whh_f, Whh_b, bih_f, bhh_f, bih_b, bhh_b,
                                          xgf, xgb, y0f, y0b, bars);
  const size_t WO = (size_t)3072 * 1024;
  gemm_bf16<short, 0><<<dim3(64, 24), blk, 0, stream>>>(y0f, 1024, Wih_f + WO, 1024, nullptr, xgf, 3072, 0, 1024, 0);
  gemm_bf16<short, 0><<<dim3(64, 24), blk, 0, stream>>>(y0b, 1024, Wih_b + WO, 1024, nullptr, xgb, 3072, 0, 1024, 0);
  gru_recur<<<dim3(64), blk, 0, stream>>>(Whh_f + WO, Whh_b + WO, bih_f + 3072, bhh_f + 3072,
                                          bih_b + 3072, bhh_b + 3072,
                                          xgf, xgb, y1f, y1b, bars + 32);
  final_dot<<<dim3(64), blk, 0, stream>>>(y1f, y1b, Wo, bo, partials);
  final_reduce<<<dim3(1), dim3(64), 0, stream>>>(partials, out);
}

// Round 4
// 2633.953 us; speedup vs baseline: 4.1853x; 2.2422x over previous
//
#include <hip/hip_runtime.h>

typedef __attribute__((ext_vector_type(8))) short bf16x8;
typedef __attribute__((ext_vector_type(4))) float f32x4;

__device__ __forceinline__ short f2bf(float f) {
  union { float f; unsigned u; } v; v.f = f;
  unsigned r = (v.u + 0x7fffu + ((v.u >> 16) & 1u)) >> 16;
  return (short)r;
}
__device__ __forceinline__ float bf2f(short s) {
  union { unsigned u; float f; } v; v.u = ((unsigned)(unsigned short)s) << 16;
  return v.f;
}
__device__ __forceinline__ float sigmf(float x) { return 1.f / (1.f + __expf(-x)); }

__device__ __forceinline__ void stage_row_f32(const float* __restrict__ src, short* dst,
                                              int kb, int k0, int K) {
  if (kb + k0 + 15 < K) {
    const f32x4* p4 = (const f32x4*)src;
#pragma unroll
    for (int g = 0; g < 4; g++) {
      f32x4 v = p4[g];
      dst[g * 4 + 0] = f2bf(v.x); dst[g * 4 + 1] = f2bf(v.y);
      dst[g * 4 + 2] = f2bf(v.z); dst[g * 4 + 3] = f2bf(v.w);
    }
  } else {
#pragma unroll
    for (int j = 0; j < 16; j++) {
      float v = (kb + k0 + j < K) ? src[j] : 0.f;
      dst[j] = f2bf(v);
    }
  }
}

// Input projection: C = relu(A @ W^T + bias), A fp32 [B,T,K] (logical row r=t*32+b at
// physical row b*256+t), C bf16 in chunk-16 layout:
//   elem(r=t*32+b, col) at ((t*64 + (col>>4))*512 + b*16 + (col&15)).
__global__ __launch_bounds__(256) void proj_gemm(
    const float* __restrict__ A, int lda,
    const float* __restrict__ W, int ldw,
    const float* __restrict__ bias,
    short* __restrict__ C, int coloff, int K) {
  __shared__ short As[128][40];
  __shared__ short Bs[128][40];
  const int tid = threadIdx.x;
  const int m0 = blockIdx.x << 7, n0 = blockIdx.y << 7;
  const int w = tid >> 6, lane = tid & 63, m16 = lane & 15, q = lane >> 4;
  const f32x4 vzero = {0.f, 0.f, 0.f, 0.f};
  f32x4 acc[2][8];
#pragma unroll
  for (int mt = 0; mt < 2; mt++)
#pragma unroll
    for (int nt = 0; nt < 8; nt++) acc[mt][nt] = vzero;

  const int nk = (K + 31) >> 5;
  const int r = tid >> 1, k0 = (tid & 1) << 4;
  for (int kc = 0; kc < nk; kc++) {
    const int kb = kc << 5;
    {
      const int gr = m0 + r;
      const size_t arow = (size_t)(gr & 31) * 256 + (size_t)(gr >> 5);
      stage_row_f32(A + arow * (size_t)lda + kb + k0, &As[r][k0], kb, k0, K);
    }
    {
      const float* bp = W + (size_t)(n0 + r) * ldw + kb + k0;
      stage_row_f32(bp, &Bs[r][k0], kb, k0, K);
    }
    __syncthreads();
    bf16x8 af[2], bfv[8];
#pragma unroll
    for (int mt = 0; mt < 2; mt++)
      af[mt] = *(const bf16x8*)&As[(w << 5) + (mt << 4) + m16][q << 3];
#pragma unroll
    for (int nt = 0; nt < 8; nt++)
      bfv[nt] = *(const bf16x8*)&Bs[(nt << 4) + m16][q << 3];
#pragma unroll
    for (int mt = 0; mt < 2; mt++)
#pragma unroll
      for (int nt = 0; nt < 8; nt++)
        acc[mt][nt] = __builtin_amdgcn_mfma_f32_16x16x32_bf16(af[mt], bfv[nt], acc[mt][nt], 0, 0, 0);
    __syncthreads();
  }
#pragma unroll
  for (int mt = 0; mt < 2; mt++)
#pragma unroll
    for (int nt = 0; nt < 8; nt++)
#pragma unroll
      for (int i = 0; i < 4; i++) {
        const int grow = m0 + (w << 5) + (mt << 4) + (q << 2) + i;
        const int gcol = n0 + (nt << 4) + m16;
        float v = fmaxf(acc[mt][nt][i] + bias[gcol], 0.f);
        const int col = coloff + gcol;
        const int tt = grow >> 5, b = grow & 31;
        C[((size_t)tt * 64 + (col >> 4)) * 512 + b * 16 + (col & 15)] = f2bf(v);
      }
}

// Fused 2-layer x 2-direction GRU recurrence, all pipelined in ONE kernel.
// grid = 256 blocks = 4 groups x 64: group 0=L0f, 1=L0b, 2=L1f, 3=L1b.
// Block owns 16 hidden dims. Weights [Whh_slice | Wih_slice] (96 rows x 1024)
// live in VGPRs as bf16 A-frags (192 VGPRs). Per step, per wave (K-slice 512):
// waves 0-1 accumulate h-part (Whh @ y_self[t-1]), waves 2-3 x-part (Wih @ src[t]).
// Sync: distributed per-block flags, relaxed agent-scope atomics (round-2-proven
// primitives, no fences -> no cache nukes). Data y/src read with PLAIN cached loads:
// safe since kernel-start invalidates L1/L2 and every line is first read only after
// its producer's sc1 stores committed to MALL (flag protocol) -> post-commit L2 fills,
// shared across same-XCD consumers. Waits are acyclic: L0 -> self; L1 -> self + L0.
__global__ __launch_bounds__(256, 1) void gru_fused(
    const float* __restrict__ Whh_f, const float* __restrict__ Whh_b,
    const float* __restrict__ Wih_f, const float* __restrict__ Wih_b,
    const float* __restrict__ bih_f, const float* __restrict__ bhh_f,
    const float* __restrict__ bih_b, const float* __restrict__ bhh_b,
    const short* __restrict__ x0,
    short* __restrict__ y0f, short* __restrict__ y0b,
    short* __restrict__ y1f, short* __restrict__ y1b,
    int* __restrict__ ctrl) {
  const int group = blockIdx.x >> 6;  // 0..3
  const int g = blockIdx.x & 63;
  const size_t WL = (size_t)3072 * 1024;

  const float* Wrec; const float* Win; const float* bih; const float* bhh;
  const short* src; short* y; int* ownf; const int* srcf;
  switch (group) {
    case 0:  Wrec = Whh_f;      Win = Wih_f;      bih = bih_f;        bhh = bhh_f;
             src = x0;  y = y0f; ownf = ctrl;       srcf = nullptr;    break;
    case 1:  Wrec = Whh_b;      Win = Wih_b;      bih = bih_b;        bhh = bhh_b;
             src = x0;  y = y0b; ownf = ctrl + 64;  srcf = nullptr;    break;
    case 2:  Wrec = Whh_f + WL; Win = Wih_f + WL; bih = bih_f + 3072; bhh = bhh_f + 3072;
             src = y0f; y = y1f; ownf = ctrl + 128; srcf = ctrl;       break;
    default: Wrec = Whh_b + WL; Win = Wih_b + WL; bih = bih_b + 3072; bhh = bhh_b + 3072;
             src = y0b; y = y1b; ownf = ctrl + 192; srcf = ctrl + 64;  break;
  }

  const int tid = threadIdx.x;
  const int w = tid >> 6, lane = tid & 63, m16 = lane & 15, q = lane >> 4;
  const int d0 = g << 4;

  // ---- preload [Whh|Wih] slice as A-frags (fp32 -> bf16): 3 tiles x 16 ksteps ----
  const float* Wsrc = (w < 2) ? Wrec : Win;
  const int kb0 = (w & 1) << 9;
  bf16x8 a[3][16];
#pragma unroll
  for (int mt = 0; mt < 3; mt++) {
    const size_t row = (size_t)(mt << 10) + d0 + m16;
#pragma unroll
    for (int ks = 0; ks < 16; ks++) {
      const int k = kb0 + (ks << 5) + (q << 3);
      const f32x4* wp = (const f32x4*)(Wsrc + row * 1024 + k);
      f32x4 lo = wp[0], hi = wp[1];
      bf16x8 t;
      t[0] = f2bf(lo.x); t[1] = f2bf(lo.y); t[2] = f2bf(lo.z); t[3] = f2bf(lo.w);
      t[4] = f2bf(hi.x); t[5] = f2bf(hi.y); t[6] = f2bf(hi.z); t[7] = f2bf(hi.w);
      a[mt][ks] = t;
    }
  }

  // elementwise ownership: dd = tid&15 (local dim), batches {bq, bq+16}
  const int dd = tid & 15, bq = tid >> 4;
  const int dg = d0 + dd;
  const float Cr = bih[dg] + bhh[dg];
  const float Cz = bih[1024 + dg] + bhh[1024 + dg];
  const float bni = bih[2048 + dg], bnh = bhh[2048 + dg];
  float h[2] = {0.f, 0.f};

  __shared__ float hgp[4 * 48 * 33];  // [wave][3 gates x 16 dims][batch(+pad)]
  __shared__ short hout[32 * 18];
  const f32x4 vzero = {0.f, 0.f, 0.f, 0.f};

  for (int t = 0; t < 256; t++) {
    // ---- wait for dependencies (wave 0 polls, others wait at barrier) ----
    if (t > 0 || srcf) {
      if (w == 0) {
        for (;;) {
          int ok = 1;
          if (t > 0)
            ok &= (__hip_atomic_load(ownf + lane, __ATOMIC_RELAXED,
                                     __HIP_MEMORY_SCOPE_AGENT) >= t);
          if (srcf)
            ok &= (__hip_atomic_load(srcf + lane, __ATOMIC_RELAXED,
                                     __HIP_MEMORY_SCOPE_AGENT) >= t + 1);
          if (__all(ok)) break;
          __builtin_amdgcn_s_sleep(1);
        }
      }
      __syncthreads();
    }

    f32x4 acc[3][2];
#pragma unroll
    for (int mt = 0; mt < 3; mt++) { acc[mt][0] = vzero; acc[mt][1] = vzero; }

    const bool active = (w >= 2) || (t > 0);
    if (active) {
      // waves 0-1: y_self[t-1]; waves 2-3: src[t]; both in chunk-16 layout
      const short* buf = (w < 2) ? (y + (size_t)(t - 1) * 32768)
                                 : (src + (size_t)t * 32768);
      const int boff = (q & 1) << 3;
#pragma unroll
      for (int ks = 0; ks < 16; ks++) {
        const int c16 = ((w & 1) << 5) + (ks << 1) + (q >> 1);
        const short* cp = buf + (size_t)c16 * 512 + boff;
        bf16x8 b0 = *(const bf16x8*)(cp + m16 * 16);
        bf16x8 b1 = *(const bf16x8*)(cp + (m16 + 16) * 16);
#pragma unroll
        for (int mt = 0; mt < 3; mt++) {
          acc[mt][0] = __builtin_amdgcn_mfma_f32_16x16x32_bf16(a[mt][ks], b0, acc[mt][0], 0, 0, 0);
          acc[mt][1] = __builtin_amdgcn_mfma_f32_16x16x32_bf16(a[mt][ks], b1, acc[mt][1], 0, 0, 0);
        }
      }
    }
#pragma unroll
    for (int mt = 0; mt < 3; mt++)
#pragma unroll
      for (int nt = 0; nt < 2; nt++)
#pragma unroll
        for (int i = 0; i < 4; i++)
          hgp[((size_t)w * 48 + mt * 16 + (q << 2) + i) * 33 + (nt << 4) + m16] = acc[mt][nt][i];
    __syncthreads();

    // gates: waves 0-1 partials = h-part, waves 2-3 = x-part (kept separate for n-gate)
#pragma unroll
    for (int k2 = 0; k2 < 2; k2++) {
      const int b = bq + (k2 << 4);
      float rs = 0.f, zs = 0.f;
#pragma unroll
      for (int w4 = 0; w4 < 4; w4++) {
        rs += hgp[((size_t)w4 * 48 + dd) * 33 + b];
        zs += hgp[((size_t)w4 * 48 + 16 + dd) * 33 + b];
      }
      const float hn = hgp[(0 * 48 + 32 + dd) * 33 + b] + hgp[(1 * 48 + 32 + dd) * 33 + b];
      const float xn = hgp[(2 * 48 + 32 + dd) * 33 + b] + hgp[(3 * 48 + 32 + dd) * 33 + b];
      const float rr = sigmf(rs + Cr);
      const float zz = sigmf(zs + Cz);
      const float nn = tanhf(xn + bni + rr * (hn + bnh));
      h[k2] = (1.f - zz) * nn + zz * h[k2];
      hout[b * 18 + dd] = f2bf(h[k2]);
    }
    __syncthreads();

    // store own chunk (t, g): 512 elems = 1024 B, 4 B per thread, sc1 (MALL)
    {
      const int b = tid >> 3, dl = (tid & 7) << 1;
      const unsigned lo16 = (unsigned short)hout[b * 18 + dl];
      const unsigned hi16 = (unsigned short)hout[b * 18 + dl + 1];
      __hip_atomic_store((unsigned*)(y + ((size_t)t * 64 + g) * 512 + b * 16 + dl),
                         lo16 | (hi16 << 16), __ATOMIC_RELAXED, __HIP_MEMORY_SCOPE_AGENT);
    }
    __builtin_amdgcn_s_waitcnt(0);  // this thread's stores committed
    __syncthreads();                // whole block's stores committed
    if (tid == 0)
      __hip_atomic_store(ownf + g, t + 1, __ATOMIC_RELAXED, __HIP_MEMORY_SCOPE_AGENT);
  }
}

// y1 f/b in chunk-16 layout: elem(r=t*32+b, c) at ((t*64 + (c>>4))*512 + b*16 + (c&15))
__global__ __launch_bounds__(256) void final_dot(
    const short* __restrict__ yF, const short* __restrict__ yB,
    const float* __restrict__ Wo, const float* __restrict__ bo,
    float* __restrict__ partials) {
  const int w = threadIdx.x >> 6, lane = threadIdx.x & 63;
  __shared__ float red[4];
  float acc = 0.f;
  const int r0 = (blockIdx.x << 7) + (w << 5);
  for (int rr = 0; rr < 32; rr++) {
    const int r = r0 + rr;
    const size_t rbase = (size_t)(r >> 5) * 32768 + (size_t)(r & 31) * 16;
    float s = 0.f;
    for (int c = lane; c < 1024; c += 64) {
      const size_t idx = rbase + (size_t)(c >> 4) * 512 + (c & 15);
      s += (bf2f(yF[idx]) + bf2f(yB[idx])) * Wo[c];
    }
#pragma unroll
    for (int off = 32; off > 0; off >>= 1) s += __shfl_down(s, off);
    if (lane == 0) acc += sigmf(s + bo[0]);
  }
  if (lane == 0) red[w] = acc;
  __syncthreads();
  if (threadIdx.x == 0) partials[blockIdx.x] = red[0] + red[1] + red[2] + red[3];
}

__global__ void final_reduce(const float* __restrict__ partials, float* __restrict__ out) {
  float s = partials[threadIdx.x];
#pragma unroll
  for (int off = 32; off > 0; off >>= 1) s += __shfl_down(s, off);
  if (threadIdx.x == 0) out[0] = s * (1.f / 8192.f);
}

extern "C" void kernel_launch(void* const* d_in, const int* in_sizes, int n_in,
                              void* d_out, int out_size, void* d_ws, size_t ws_size,
                              hipStream_t stream) {
  const float* in_x  = (const float*)d_in[0];   // [32,256,72]
  const float* in_c  = (const float*)d_in[1];   // [32,256,80]
  const float* Wc    = (const float*)d_in[2];   // [512,80]
  const float* bc    = (const float*)d_in[3];
  const float* Wi    = (const float*)d_in[4];   // [512,72]
  const float* bi    = (const float*)d_in[5];
  const float* Wih_f = (const float*)d_in[6];   // [2,3072,1024]
  const float* Whh_f = (const float*)d_in[7];
  const float* bih_f = (const float*)d_in[8];
  const float* bhh_f = (const float*)d_in[9];
  const float* Wih_b = (const float*)d_in[10];
  const float* Whh_b = (const float*)d_in[11];
  const float* bih_b = (const float*)d_in[12];
  const float* bhh_b = (const float*)d_in[13];
  const float* Wo    = (const float*)d_in[14];  // [1,1024]
  const float* bo    = (const float*)d_in[15];
  float* out = (float*)d_out;

  char* base = (char*)d_ws;
  const size_t S1 = (size_t)8192 * 1024 * 2;  // 16.78 MB per [T*B,1024] bf16 buffer
  short* x0  = (short*)(base);                // layer-0 input; reused as y1f
  short* y0f = (short*)(base + S1);
  short* y0b = (short*)(base + 2 * S1);
  short* y1b = (short*)(base + 3 * S1);
  float* partials = (float*)(base + 4 * S1);
  int* ctrl = (int*)(base + 4 * S1 + 4096);
  short* y1f = x0;  // safe: x0 chunk t is last read at L0 step t, before y1[t] write

  hipMemsetAsync(ctrl, 0, 4096, stream);

  dim3 blk(256);
  proj_gemm<<<dim3(64, 4), blk, 0, stream>>>(in_c, 80, Wc, 80, bc, x0, 0, 80);
  proj_gemm<<<dim3(64, 4), blk, 0, stream>>>(in_x, 72, Wi, 72, bi, x0, 512, 72);
  gru_fused<<<dim3(256), blk, 0, stream>>>(Whh_f, Whh_b, Wih_f, Wih_b,
                                           bih_f, bhh_f, bih_b, bhh_b,
                                           x0, y0f, y0b, y1f, y1b, ctrl);
  final_dot<<<dim3(64), blk, 0, stream>>>(y1f, y1b, Wo, bo, partials);
  final_reduce<<<dim3(1), dim3(64), 0, stream>>>(partials, out);
}